// Round 9
// baseline (198.670 us; speedup 1.0000x reference)
//
#include <hip/hip_runtime.h>

// ---------------------------------------------------------------------------
// GridMERA 16x16 forward.
// Inputs (d_in order): inputs[128,16,16,1], e1[16^4,4^4], e2[4^8],
//   iso1_0[16,16,16,4,4], iso1_1[16,16,4,16,4], iso1_2[16,4,16,16,4],
//   iso1_3[4,16,16,16,4], iso2[4,4,4,4,10], bias[10]
// Output: [128,10] fp32.
//
// Patch transform: patch p, element d lives at in[b*256 + off(p,d)],
//   off(p,d) = ((p>>2)*4 + (d>>2))*16 + (p&3)*4 + (d&3).
//
// Workspace layout (bytes):
//   tt    @ 131072   : 4*128*16*4  = 32768    (iso1 outputs, [iso][B][m*4+o])
//   M2    @ 163840   : 256*10*4    = 10240    (e2·iso2, [abcd][C])
//   vpart @ 262144   : 64*128*256*4 = 8388608 (split-K partials of v)
// ---------------------------------------------------------------------------

#define KC 64  // K-chunks in the big GEMM (K = 65536, chunk = 1024 = 4 ab-values)

typedef __attribute__((ext_vector_type(8))) short bf16x8;
typedef __attribute__((ext_vector_type(4))) float f32x4;

__device__ __forceinline__ int poff(int p, int d) {
    return ((p >> 2) * 4 + (d >> 2)) * 16 + (p & 3) * 4 + (d & 3);
}

// truncation split: x = hi + rem exactly; lo = trunc_bf16(rem).
__device__ __forceinline__ void splitf(float x, short& h, short& l) {
    unsigned u = __builtin_bit_cast(unsigned, x);
    h = (short)(u >> 16);
    float hf = __builtin_bit_cast(float, u & 0xFFFF0000u);
    float rem = x - hf;
    l = (short)(__builtin_bit_cast(unsigned, rem) >> 16);
}

// K2: one block per (batch, iso).  thread t = (i = t>>4, j = t&15), loops k.
// Reads patches straight from `in` (k1 folded in).
__global__ void __launch_bounds__(256) k2_iso(
        const float* __restrict__ i0, const float* __restrict__ i1,
        const float* __restrict__ i2, const float* __restrict__ i3,
        const float* __restrict__ in, float* __restrict__ tt) {
    int b = blockIdx.x, iso = blockIdx.y;
    int t = threadIdx.x;

    const int pid0[4] = {0, 2, 8, 11};
    const int pid1[4] = {1, 3, 12, 14};
    const int pid2[4] = {4, 7, 13, 15};
    const int siA[4] = {4096, 4096, 4096, 1024};
    const int sjA[4] = {256, 256, 64, 64};
    const int skA[4] = {16, 4, 4, 4};
    const int smA[4] = {4, 64, 1024, 16384};

    const float* iso_p = (iso == 0) ? i0 : (iso == 1) ? i1 : (iso == 2) ? i2 : i3;

    __shared__ float pX[16], pY[16], pZ[16];
    if (t < 16)      pX[t]      = in[b * 256 + poff(pid0[iso], t)];
    else if (t < 32) pY[t - 16] = in[b * 256 + poff(pid1[iso], t - 16)];
    else if (t < 48) pZ[t - 32] = in[b * 256 + poff(pid2[iso], t - 32)];
    __syncthreads();

    int i = t >> 4, j = t & 15;
    float pxy = pX[i] * pY[j];
    int sk = skA[iso], sm = smA[iso];
    const float* basep = iso_p + i * siA[iso] + j * sjA[iso];

    float acc[16];
#pragma unroll
    for (int mo = 0; mo < 16; ++mo) acc[mo] = 0.f;

    for (int k = 0; k < 16; ++k) {
        float w = pxy * pZ[k];
        const float* kp = basep + k * sk;
#pragma unroll
        for (int m = 0; m < 4; ++m) {
            float4 v = *(const float4*)(kp + m * sm);
            acc[m * 4 + 0] += w * v.x;
            acc[m * 4 + 1] += w * v.y;
            acc[m * 4 + 2] += w * v.z;
            acc[m * 4 + 3] += w * v.w;
        }
    }

    __shared__ float red[16 * 257];
    __shared__ float part[256];
#pragma unroll
    for (int mo = 0; mo < 16; ++mo) red[mo * 257 + t] = acc[mo];
    __syncthreads();
    int mo = t & 15, seg = t >> 4;
    float s = 0.f;
#pragma unroll
    for (int u = 0; u < 16; ++u) s += red[mo * 257 + seg * 16 + u];
    part[mo * 16 + seg] = s;
    __syncthreads();
    if (t < 16) {
        float o = 0.f;
#pragma unroll
        for (int s2 = 0; s2 < 16; ++s2) o += part[t * 16 + s2];
        tt[iso * 2048 + b * 16 + t] = o;
    }
}

// K3: M2[q][C] = sum_r e2[q*256+r] * iso2[r*10+C]
__global__ void k3_m2(const float* __restrict__ e2, const float* __restrict__ iso2,
                      float* __restrict__ M2) {
    __shared__ float is2[2560];
    int t = threadIdx.x;
    for (int s = t; s < 2560; s += 256) is2[s] = iso2[s];
    __syncthreads();
    int flat = blockIdx.x * 256 + t;
    int q = flat / 10, C = flat % 10;
    float acc = 0.f;
    for (int r = 0; r < 256; ++r) acc += e2[q * 256 + r] * is2[r * 10 + C];
    M2[q * 10 + C] = acc;
}

// K4 v4: MFMA split-bf16 3-pass streaming GEMM, occupancy-fixed.
// grid (64 kc, 8 ny); block 512 = 8 waves; wave wv covers batches
// [wv*16, wv*16+16) x 32 cols (2 N-tiles).  Fragment math identical to the
// verified v3 kernel with the M-tile loop (t) collapsed to a single tile.
// 512 blocks = 2/CU, 16 waves/CU = 4/SIMD -> latency hidden by TLP.
__global__ void __launch_bounds__(512, 4) k4_mfma(const float* __restrict__ e1,
                                                  const float* __restrict__ in,
                                                  float* __restrict__ vpart) {
    int kc = blockIdx.x;        // 0..63  (1024 k's = 4 ab values)
    int ny = blockIdx.y;        // 0..7   (32-col slice)
    int tid = threadIdx.x;
    int wv = tid >> 6;          // wave 0..7 = M-tile (16 batches)
    int lane = tid & 63;
    int l15 = lane & 15;
    int g = lane >> 4;          // k-group: A/B element k_loc = g*8+j
    int d0 = (g & 1) * 8;       // lane's fixed d-range within a 32-k step
    bool hic = (g & 2) != 0;    // lane's c-offset (0 or 1) within the step

    int b = wv * 16 + l15;      // this lane's batch row
    const float* xb = in + b * 256;

    // per-lane patch tables (direct from `in` via patch transform)
    float p9r[16], p10r[8], p5r;
#pragma unroll
    for (int c = 0; c < 16; ++c) p9r[c] = xb[128 + (c >> 2) * 16 + 4 + (c & 3)];   // p9
#pragma unroll
    for (int j = 0; j < 8; ++j) {
        int d = d0 + j;
        p10r[j] = xb[128 + (d >> 2) * 16 + 8 + (d & 3)];                           // p10
    }
    {
        int a = kc >> 2;
        p5r = xb[64 + (a >> 2) * 16 + 4 + (a & 3)];                                // p5
    }

    int colbase = ny * 32;
    int col0 = colbase + l15;

    f32x4 acc[2];
#pragma unroll
    for (int tn = 0; tn < 2; ++tn) acc[tn] = (f32x4){0.f, 0.f, 0.f, 0.f};

    const float* ep = e1 + ((size_t)(kc * 1024 + g * 8)) * 256;

    for (int abi = 0; abi < 4; ++abi) {          // 4 ab's per chunk
        int a2 = (kc & 3) * 4 + abi;             // p6 index for this ab
        float sab = p5r * xb[64 + (a2 >> 2) * 16 + 8 + (a2 & 3)];
#pragma unroll
        for (int cc = 0; cc < 8; ++cc) {         // 8 K-steps of 32 per ab
            // ---- B fragments: e1 rows kbase+g*8+j, cols col0 + tn*16 ----
            bf16x8 eh[2], el[2];
#pragma unroll
            for (int tn = 0; tn < 2; ++tn) {
                const float* ec = ep + (size_t)cc * 32 * 256 + col0 + tn * 16;
#pragma unroll
                for (int j = 0; j < 8; ++j) {
                    float evj = ec[(size_t)j * 256];
                    short h, l; splitf(evj, h, l);
                    eh[tn][j] = h; el[tn][j] = l;
                }
            }
            // ---- A fragments: W = sab * p9[c] * p10[d], c = 2cc + (g>>1) ----
            bf16x8 wh, wl;
            {
                float s0 = sab * p9r[2 * cc];
                float s1 = sab * p9r[2 * cc + 1];
                float s = hic ? s1 : s0;
#pragma unroll
                for (int j = 0; j < 8; ++j) {
                    float wj = s * p10r[j];
                    short h, l; splitf(wj, h, l);
                    wh[j] = h; wl[j] = l;
                }
            }
            // ---- MFMA 3-pass: Wh*Eh + Wh*El + Wl*Eh ----
#pragma unroll
            for (int tn = 0; tn < 2; ++tn) {
                acc[tn] = __builtin_amdgcn_mfma_f32_16x16x32_bf16(wh, eh[tn], acc[tn], 0, 0, 0);
                acc[tn] = __builtin_amdgcn_mfma_f32_16x16x32_bf16(wh, el[tn], acc[tn], 0, 0, 0);
                acc[tn] = __builtin_amdgcn_mfma_f32_16x16x32_bf16(wl, eh[tn], acc[tn], 0, 0, 0);
            }
        }
        ep += (size_t)256 * 256;                 // advance 256 e1 rows per ab
    }

    // ---- store: D element (row = g*4 + r, col = l15) ----
    int brow = wv * 16 + g * 4;
#pragma unroll
    for (int tn = 0; tn < 2; ++tn) {
        int col = colbase + tn * 16 + l15;
#pragma unroll
        for (int r = 0; r < 4; ++r) {
            vpart[((size_t)kc * 128 + brow + r) * 256 + col] = acc[tn][r];
        }
    }
}

// K5 v2: parallel split-K reduce (thread = col, unrolled kc) + per-batch tail.
// grid 128 (batch), block 256.
__global__ void __launch_bounds__(256) k5_final(
        const float* __restrict__ vpart, const float* __restrict__ tt,
        const float* __restrict__ M2, const float* __restrict__ bias,
        float* __restrict__ out) {
    __shared__ float v[256], A[256], Bb[256];
    __shared__ float t0[16], t1[16], t2[16], t3[16];
    int b = blockIdx.x, t = threadIdx.x;

    float s = 0.f;
#pragma unroll 8
    for (int kc = 0; kc < KC; ++kc) {
        s += vpart[((size_t)kc * 128 + b) * 256 + t];
    }
    v[t] = s;
    if (t < 16) {
        t0[t] = tt[0 * 2048 + b * 16 + t];
        t1[t] = tt[1 * 2048 + b * 16 + t];
        t2[t] = tt[2 * 2048 + b * 16 + t];
        t3[t] = tt[3 * 2048 + b * 16 + t];
    }
    __syncthreads();

    // stage1: A[a*64+fgh] = sum_e t0[e*4+a] * v[e*64+fgh]
    {
        int a = t >> 6, fgh = t & 63;
        float acc = 0.f;
#pragma unroll
        for (int e = 0; e < 4; ++e) acc += t0[e * 4 + a] * v[e * 64 + fgh];
        A[t] = acc;
    }
    __syncthreads();
    // stage2: Bb[a*64+bb*16+gh] = sum_f t1[f*4+bb] * A[a*64+f*16+gh]
    {
        int a = t >> 6, bb = (t >> 4) & 3, gh = t & 15;
        float acc = 0.f;
#pragma unroll
        for (int f = 0; f < 4; ++f) acc += t1[f * 4 + bb] * A[a * 64 + f * 16 + gh];
        Bb[t] = acc;
    }
    __syncthreads();
    // stage3: A[ab*16+c*4+h] = sum_g t2[g*4+c] * Bb[ab*16+g*4+h]
    {
        int ab = t >> 4, c = (t >> 2) & 3, h = t & 3;
        float acc = 0.f;
#pragma unroll
        for (int g = 0; g < 4; ++g) acc += t2[g * 4 + c] * Bb[ab * 16 + g * 4 + h];
        A[t] = acc;
    }
    __syncthreads();
    // stage4: w[abc*4+dd] = sum_h t3[h*4+dd] * A[abc*4+h]
    {
        int abc = t >> 2, dd = t & 3;
        float acc = 0.f;
#pragma unroll
        for (int h = 0; h < 4; ++h) acc += t3[h * 4 + dd] * A[abc * 4 + h];
        Bb[t] = acc;
    }
    __syncthreads();
    // out[C] = bias[C] + sum_q w[q] * M2[q*10+C]
    if (t < 10) {
        float acc = bias[t];
        for (int q = 0; q < 256; ++q) acc += Bb[q] * M2[q * 10 + t];
        out[b * 10 + t] = acc;
    }
}

extern "C" void kernel_launch(void* const* d_in, const int* in_sizes, int n_in,
                              void* d_out, int out_size, void* d_ws, size_t ws_size,
                              hipStream_t stream) {
    const float* in    = (const float*)d_in[0];
    const float* e1    = (const float*)d_in[1];
    const float* e2    = (const float*)d_in[2];
    const float* iso10 = (const float*)d_in[3];
    const float* iso11 = (const float*)d_in[4];
    const float* iso12 = (const float*)d_in[5];
    const float* iso13 = (const float*)d_in[6];
    const float* iso2  = (const float*)d_in[7];
    const float* bias  = (const float*)d_in[8];
    float* out = (float*)d_out;

    char* ws = (char*)d_ws;
    float* tt    = (float*)(ws + 131072);
    float* M2    = (float*)(ws + 163840);
    float* vpart = (float*)(ws + 262144);

    hipLaunchKernelGGL(k2_iso, dim3(128, 4), dim3(256), 0, stream,
                       iso10, iso11, iso12, iso13, in, tt);
    hipLaunchKernelGGL(k3_m2, dim3(10), dim3(256), 0, stream, e2, iso2, M2);
    hipLaunchKernelGGL(k4_mfma, dim3(KC, 8), dim3(512), 0, stream, e1, in, vpart);
    hipLaunchKernelGGL(k5_final, dim3(128), dim3(256), 0, stream,
                       vpart, tt, M2, bias, out);
}

// Round 10
// 196.090 us; speedup vs baseline: 1.0132x; 1.0132x over previous
//
#include <hip/hip_runtime.h>

// ---------------------------------------------------------------------------
// GridMERA 16x16 forward.
// Inputs (d_in order): inputs[128,16,16,1], e1[16^4,4^4], e2[4^8],
//   iso1_0[16,16,16,4,4], iso1_1[16,16,4,16,4], iso1_2[16,4,16,16,4],
//   iso1_3[4,16,16,16,4], iso2[4,4,4,4,10], bias[10]
// Output: [128,10] fp32.
//
// Patch transform: patch p, element d lives at in[b*256 + off(p,d)],
//   off(p,d) = ((p>>2)*4 + (d>>2))*16 + (p&3)*4 + (d&3).
//
// Workspace layout (bytes):
//   tt    @ 131072 : 4*128*16*4 = 32768     (iso1 outputs)
//   M2    @ 163840 : 256*10*4   = 10240     (e2·iso2)
//   vpart @ 262144 : [b][KCC][256] f32; KCC=256 fast path (33.5MB) or 64.
// ---------------------------------------------------------------------------

typedef __attribute__((ext_vector_type(8))) short bf16x8;
typedef __attribute__((ext_vector_type(4))) float f32x4;

__device__ __forceinline__ int poff(int p, int d) {
    return ((p >> 2) * 4 + (d >> 2)) * 16 + (p & 3) * 4 + (d & 3);
}

// truncation split: x = hi + rem exactly; lo = trunc_bf16(rem).
__device__ __forceinline__ void splitf(float x, short& h, short& l) {
    unsigned u = __builtin_bit_cast(unsigned, x);
    h = (short)(u >> 16);
    float hf = __builtin_bit_cast(float, u & 0xFFFF0000u);
    float rem = x - hf;
    l = (short)(__builtin_bit_cast(unsigned, rem) >> 16);
}

// K2: one block per (batch, iso).  (unchanged, ~5us)
__global__ void __launch_bounds__(256) k2_iso(
        const float* __restrict__ i0, const float* __restrict__ i1,
        const float* __restrict__ i2, const float* __restrict__ i3,
        const float* __restrict__ in, float* __restrict__ tt) {
    int b = blockIdx.x, iso = blockIdx.y;
    int t = threadIdx.x;

    const int pid0[4] = {0, 2, 8, 11};
    const int pid1[4] = {1, 3, 12, 14};
    const int pid2[4] = {4, 7, 13, 15};
    const int siA[4] = {4096, 4096, 4096, 1024};
    const int sjA[4] = {256, 256, 64, 64};
    const int skA[4] = {16, 4, 4, 4};
    const int smA[4] = {4, 64, 1024, 16384};

    const float* iso_p = (iso == 0) ? i0 : (iso == 1) ? i1 : (iso == 2) ? i2 : i3;

    __shared__ float pX[16], pY[16], pZ[16];
    if (t < 16)      pX[t]      = in[b * 256 + poff(pid0[iso], t)];
    else if (t < 32) pY[t - 16] = in[b * 256 + poff(pid1[iso], t - 16)];
    else if (t < 48) pZ[t - 32] = in[b * 256 + poff(pid2[iso], t - 32)];
    __syncthreads();

    int i = t >> 4, j = t & 15;
    float pxy = pX[i] * pY[j];
    int sk = skA[iso], sm = smA[iso];
    const float* basep = iso_p + i * siA[iso] + j * sjA[iso];

    float acc[16];
#pragma unroll
    for (int mo = 0; mo < 16; ++mo) acc[mo] = 0.f;

    for (int k = 0; k < 16; ++k) {
        float w = pxy * pZ[k];
        const float* kp = basep + k * sk;
#pragma unroll
        for (int m = 0; m < 4; ++m) {
            float4 v = *(const float4*)(kp + m * sm);
            acc[m * 4 + 0] += w * v.x;
            acc[m * 4 + 1] += w * v.y;
            acc[m * 4 + 2] += w * v.z;
            acc[m * 4 + 3] += w * v.w;
        }
    }

    __shared__ float red[16 * 257];
    __shared__ float part[256];
#pragma unroll
    for (int mo = 0; mo < 16; ++mo) red[mo * 257 + t] = acc[mo];
    __syncthreads();
    int mo = t & 15, seg = t >> 4;
    float s = 0.f;
#pragma unroll
    for (int u = 0; u < 16; ++u) s += red[mo * 257 + seg * 16 + u];
    part[mo * 16 + seg] = s;
    __syncthreads();
    if (t < 16) {
        float o = 0.f;
#pragma unroll
        for (int s2 = 0; s2 < 16; ++s2) o += part[t * 16 + s2];
        tt[iso * 2048 + b * 16 + t] = o;
    }
}

// K3: M2[q][C] = sum_r e2[q*256+r] * iso2[r*10+C]
__global__ void k3_m2(const float* __restrict__ e2, const float* __restrict__ iso2,
                      float* __restrict__ M2) {
    __shared__ float is2[2560];
    int t = threadIdx.x;
    for (int s = t; s < 2560; s += 256) is2[s] = iso2[s];
    __syncthreads();
    int flat = blockIdx.x * 256 + t;
    int q = flat / 10, C = flat % 10;
    float acc = 0.f;
    for (int r = 0; r < 256; ++r) acc += e2[q * 256 + r] * is2[r * 10 + C];
    M2[q * 10 + C] = acc;
}

// K4 v5: MFMA split-bf16 3-pass GEMM; abi-split for occupancy.
// Each block covers NABI consecutive kcc slices (kcc = 256 e1 rows; a=kcc>>4,
// a2=kcc&15) x 64 cols.  Block 256 thr = 4 waves (mg x ngr); each wave:
// 4 M-tiles (64 batches) x 2 N-tiles (32 cols) -- v3's verified fragment math.
// Fast path NABI=1: grid(256,4) = 1024 blocks -> 4 blocks/CU, 4 waves/SIMD.
// p9 loaded per (tile, step) from L2 instead of a 64-reg table (VGPR <= 128).
// vpart layout [b][kcc_total][256]; slot = blockIdx.x.
template<int NABI>
__global__ void __launch_bounds__(256, 4) k4_mfma(const float* __restrict__ e1,
                                                  const float* __restrict__ in,
                                                  float* __restrict__ vpart,
                                                  int kcc_total) {
    int bx = blockIdx.x;        // kcc-group
    int ny = blockIdx.y;        // 0..3 (64-col slice)
    int tid = threadIdx.x;
    int wv = tid >> 6;          // wave 0..3
    int lane = tid & 63;
    int mg = wv >> 1;           // M-group (batches mg*64..+63)
    int ngr = wv & 1;           // N-group (32 cols)
    int l15 = lane & 15;
    int g = lane >> 4;          // k-group: A/B element k_loc = g*8+j
    int d0 = (g & 1) * 8;       // lane's fixed d-range within a 32-k step
    int hic = (g & 2) ? 1 : 0;  // lane's c-offset within the step

    // batch-row pointers for this lane's 4 M-tiles
    const float* xb[4];
#pragma unroll
    for (int t = 0; t < 4; ++t) xb[t] = in + (mg * 64 + t * 16 + l15) * 256;

    // p10 table (persistent): p10[b][d] = in[b][poff(10, d)]
    float p10r[4][8];
#pragma unroll
    for (int t = 0; t < 4; ++t)
#pragma unroll
        for (int j = 0; j < 8; ++j) {
            int d = d0 + j;
            p10r[t][j] = xb[t][128 + (d >> 2) * 16 + 8 + (d & 3)];
        }

    int colbase = ny * 64 + ngr * 32;
    int col0 = colbase + l15;

    f32x4 acc[4][2];
#pragma unroll
    for (int t = 0; t < 4; ++t)
#pragma unroll
        for (int tn = 0; tn < 2; ++tn)
            acc[t][tn] = (f32x4){0.f, 0.f, 0.f, 0.f};

    for (int ai = 0; ai < NABI; ++ai) {
        int kcc = bx * NABI + ai;
        int a = kcc >> 4, a2 = kcc & 15;
        float sab[4];
#pragma unroll
        for (int t = 0; t < 4; ++t)
            sab[t] = xb[t][64 + (a >> 2) * 16 + 4 + (a & 3)]      // p5[a]
                   * xb[t][64 + (a2 >> 2) * 16 + 8 + (a2 & 3)];   // p6[a2]

        const float* ep = e1 + ((size_t)(kcc * 256 + g * 8)) * 256;

        for (int cc = 0; cc < 8; ++cc) {         // 8 K-steps of 32
            // ---- B fragments ----
            bf16x8 eh[2], el[2];
#pragma unroll
            for (int tn = 0; tn < 2; ++tn) {
                const float* ec = ep + (size_t)cc * 32 * 256 + col0 + tn * 16;
#pragma unroll
                for (int j = 0; j < 8; ++j) {
                    short h, l; splitf(ec[(size_t)j * 256], h, l);
                    eh[tn][j] = h; el[tn][j] = l;
                }
            }
            // ---- A fragments + MFMA per M-tile ----
            int c = 2 * cc + hic;
            int p9off = 128 + (c >> 2) * 16 + 4 + (c & 3);
#pragma unroll
            for (int t = 0; t < 4; ++t) {
                float s = sab[t] * xb[t][p9off];
                bf16x8 wh, wl;
#pragma unroll
                for (int j = 0; j < 8; ++j) {
                    short h, l; splitf(s * p10r[t][j], h, l);
                    wh[j] = h; wl[j] = l;
                }
#pragma unroll
                for (int tn = 0; tn < 2; ++tn) {
                    acc[t][tn] = __builtin_amdgcn_mfma_f32_16x16x32_bf16(wh, eh[tn], acc[t][tn], 0, 0, 0);
                    acc[t][tn] = __builtin_amdgcn_mfma_f32_16x16x32_bf16(wh, el[tn], acc[t][tn], 0, 0, 0);
                    acc[t][tn] = __builtin_amdgcn_mfma_f32_16x16x32_bf16(wl, eh[tn], acc[t][tn], 0, 0, 0);
                }
            }
        }
    }

    // ---- store: D element (row = g*4 + r, col = l15); vpart[b][kcc][col] ----
#pragma unroll
    for (int t = 0; t < 4; ++t) {
        int brow = mg * 64 + t * 16 + g * 4;
#pragma unroll
        for (int tn = 0; tn < 2; ++tn) {
            int col = colbase + tn * 16 + l15;
#pragma unroll
            for (int r = 0; r < 4; ++r) {
                vpart[((size_t)(brow + r) * kcc_total + bx) * 256 + col] = acc[t][tn][r];
            }
        }
    }
}

// K5 v3: contiguous split-K reduce (vpart[b][KCC][256]) + per-batch tail.
template<int KCC>
__global__ void __launch_bounds__(256) k5_final(
        const float* __restrict__ vpart, const float* __restrict__ tt,
        const float* __restrict__ M2, const float* __restrict__ bias,
        float* __restrict__ out) {
    __shared__ float v[256], A[256], Bb[256];
    __shared__ float t0[16], t1[16], t2[16], t3[16];
    int b = blockIdx.x, t = threadIdx.x;

    const float* vp = vpart + (size_t)b * KCC * 256 + t;
    float s = 0.f;
#pragma unroll 16
    for (int k = 0; k < KCC; ++k) s += vp[(size_t)k * 256];
    v[t] = s;
    if (t < 16) {
        t0[t] = tt[0 * 2048 + b * 16 + t];
        t1[t] = tt[1 * 2048 + b * 16 + t];
        t2[t] = tt[2 * 2048 + b * 16 + t];
        t3[t] = tt[3 * 2048 + b * 16 + t];
    }
    __syncthreads();

    // stage1: A[a*64+fgh] = sum_e t0[e*4+a] * v[e*64+fgh]
    {
        int a = t >> 6, fgh = t & 63;
        float acc = 0.f;
#pragma unroll
        for (int e = 0; e < 4; ++e) acc += t0[e * 4 + a] * v[e * 64 + fgh];
        A[t] = acc;
    }
    __syncthreads();
    // stage2: Bb[a*64+bb*16+gh] = sum_f t1[f*4+bb] * A[a*64+f*16+gh]
    {
        int a = t >> 6, bb = (t >> 4) & 3, gh = t & 15;
        float acc = 0.f;
#pragma unroll
        for (int f = 0; f < 4; ++f) acc += t1[f * 4 + bb] * A[a * 64 + f * 16 + gh];
        Bb[t] = acc;
    }
    __syncthreads();
    // stage3: A[ab*16+c*4+h] = sum_g t2[g*4+c] * Bb[ab*16+g*4+h]
    {
        int ab = t >> 4, c = (t >> 2) & 3, h = t & 3;
        float acc = 0.f;
#pragma unroll
        for (int g = 0; g < 4; ++g) acc += t2[g * 4 + c] * Bb[ab * 16 + g * 4 + h];
        A[t] = acc;
    }
    __syncthreads();
    // stage4: w[abc*4+dd] = sum_h t3[h*4+dd] * A[abc*4+h]
    {
        int abc = t >> 2, dd = t & 3;
        float acc = 0.f;
#pragma unroll
        for (int h = 0; h < 4; ++h) acc += t3[h * 4 + dd] * A[abc * 4 + h];
        Bb[t] = acc;
    }
    __syncthreads();
    // out[C] = bias[C] + sum_q w[q] * M2[q*10+C]
    if (t < 10) {
        float acc = bias[t];
        for (int q = 0; q < 256; ++q) acc += Bb[q] * M2[q * 10 + t];
        out[b * 10 + t] = acc;
    }
}

extern "C" void kernel_launch(void* const* d_in, const int* in_sizes, int n_in,
                              void* d_out, int out_size, void* d_ws, size_t ws_size,
                              hipStream_t stream) {
    const float* in    = (const float*)d_in[0];
    const float* e1    = (const float*)d_in[1];
    const float* e2    = (const float*)d_in[2];
    const float* iso10 = (const float*)d_in[3];
    const float* iso11 = (const float*)d_in[4];
    const float* iso12 = (const float*)d_in[5];
    const float* iso13 = (const float*)d_in[6];
    const float* iso2  = (const float*)d_in[7];
    const float* bias  = (const float*)d_in[8];
    float* out = (float*)d_out;

    char* ws = (char*)d_ws;
    float* tt    = (float*)(ws + 131072);
    float* M2    = (float*)(ws + 163840);
    float* vpart = (float*)(ws + 262144);

    hipLaunchKernelGGL(k2_iso, dim3(128, 4), dim3(256), 0, stream,
                       iso10, iso11, iso12, iso13, in, tt);
    hipLaunchKernelGGL(k3_m2, dim3(10), dim3(256), 0, stream, e2, iso2, M2);

    // Fast path needs vpart = 128*256*256*4 = 33.5 MB of scratch.
    size_t need = (size_t)262144 + (size_t)128 * 256 * 256 * 4;
    if (ws_size >= need) {
        hipLaunchKernelGGL(k4_mfma<1>, dim3(256, 4), dim3(256), 0, stream,
                           e1, in, vpart, 256);
        hipLaunchKernelGGL(k5_final<256>, dim3(128), dim3(256), 0, stream,
                           vpart, tt, M2, bias, out);
    } else {
        hipLaunchKernelGGL(k4_mfma<4>, dim3(64, 4), dim3(256), 0, stream,
                           e1, in, vpart, 64);
        hipLaunchKernelGGL(k5_final<64>, dim3(128), dim3(256), 0, stream,
                           vpart, tt, M2, bias, out);
    }
}